// Round 7
// baseline (435.670 us; speedup 1.0000x reference)
//
#include <hip/hip_runtime.h>

// 4D conv net, MI355X. S=30, B=2, ch 1->10->10->1, kernel 3^4, pad 1, ReLU.
// out = net(x,w) + net(x,w_swap), w_swap has (k1,k2)<->(k3,k4).
// R7: all layers as 32x32x16 bf16 MFMA, M = 32 padded t-positions, K = 16
// channels, N = k4*10+co. Cross-k4 combine in epilogue via per-wave LDS.
// R8: XCD-chunk swizzle, full-line stores, barrier-free epilogue.
// R12: launch_bounds(256,2) + uniform straight-line tap body.
// R13: layer 0 K-packed (9 taps -> 1, 12 MFMAs) as conv0_k.
// R14: conv_k VGPR=76 proved the depth-1 prefetch STILL never materialized:
// the rotate copies F=FN right after the MFMAs let the allocator sink the
// FN loads to the copy point -> waitcnt ~300 cy after issue < 500-900 cy
// L3/HBM first-touch latency -> every tap stalls. Fix: ping-pong register
// double-buffer (Fa/Ba <-> Fb/Bb), NO copies, sched_barrier(0) pins each
// load cluster before the other state's MFMA block; waitcnt pass emits
// counted vmcnt (9 in flight across the MFMAs). Unroll-by-2, 1/2-tap tail.
// Verify: VGPR_Count ~110-135.

static constexpr int S  = 30;
static constexpr long S4 = 810000;
static constexpr size_t PLANE = 32768;                  // 32*32*16*2 B
static constexpr size_t YBYTES = (size_t)1800 * PLANE;  // [b(2)][g1][g2]

typedef __bf16 bf16x8 __attribute__((ext_vector_type(8)));
typedef float  f32x16 __attribute__((ext_vector_type(16)));
typedef unsigned int  u32;
typedef unsigned short u16;

static __device__ __forceinline__ u16 f2bf(float f) {
    u32 u = __builtin_bit_cast(u32, f);
    return (u16)((u + 0x7fffu + ((u >> 16) & 1u)) >> 16);
}

// ---------------------------------------------------------------------------
// B-fragment tables.
// Main: [set(6)][k12(9)][k3(3)][lane(64)] uint4 (sets 0/1 unused).
// L0-packed (appended): [branch(2)][k3(3)][lane(64)] uint4,
//   B[k=k12][n=k4*10+co] = w1[co, perm(k1,k2,k3,k4)], k12 = hl*8+j (<9).
__global__ __launch_bounds__(256) void fragprep_k(u32* __restrict__ ft,
    const float* __restrict__ w1, const float* __restrict__ w2,
    const float* __restrict__ w3)
{
    const int gid = blockIdx.x * 256 + threadIdx.x;
    if (gid >= 6 * 27 * 64 + 2 * 3 * 64) return;
    const int lane = gid & 63;
    const int n = lane & 31, hl = lane >> 5;
    u16 us[8];
#pragma unroll
    for (int j = 0; j < 8; ++j) us[j] = 0;

    if (gid < 6 * 27 * 64) {
        int r = gid >> 6;
        const int k3 = r % 3; r /= 3;
        const int k12 = r % 9; const int set = r / 9;
        const int layer = set >> 1, swap = set & 1;
        const int k1 = k12 / 3, k2 = k12 % 3;
        if (n < 30) {
            const int k4 = (n < 10) ? 0 : ((n < 20) ? 1 : 2);
            const int co = n - 10 * k4;
            const int i1 = swap ? k3 : k1, i2 = swap ? k4 : k2;
            const int i3 = swap ? k1 : k3, i4 = swap ? k2 : k4;
            const int widx = ((i1 * 3 + i2) * 3 + i3) * 3 + i4;
#pragma unroll
            for (int j = 0; j < 8; ++j) {
                const int k = hl * 8 + j;
                float wv = 0.f;
                if (layer == 0) { if (k == 0) wv = w1[co * 81 + widx]; }
                else if (layer == 1) { if (k < 10) wv = w2[(co * 10 + k) * 81 + widx]; }
                else { if (k < 10 && co == 0) wv = w3[k * 81 + widx]; }
                us[j] = f2bf(wv);
            }
        }
    } else {
        const int idx = gid - 6 * 27 * 64;       // 0..383
        int r = idx >> 6;                        // 0..5
        const int k3 = r % 3, swap = r / 3;
        if (n < 30) {
            const int k4 = (n < 10) ? 0 : ((n < 20) ? 1 : 2);
            const int co = n - 10 * k4;
#pragma unroll
            for (int j = 0; j < 8; ++j) {
                const int k12 = hl * 8 + j;
                if (k12 < 9) {
                    const int k1 = k12 / 3, k2 = k12 % 3;
                    const int i1 = swap ? k3 : k1, i2 = swap ? k4 : k2;
                    const int i3 = swap ? k1 : k3, i4 = swap ? k2 : k4;
                    const int widx = ((i1 * 3 + i2) * 3 + i3) * 3 + i4;
                    us[j] = f2bf(w1[co * 81 + widx]);
                }
            }
        }
    }
    u32* o = ft + (size_t)gid * 4;
    o[0] = (u32)us[0] | ((u32)us[1] << 16);
    o[1] = (u32)us[2] | ((u32)us[3] << 16);
    o[2] = (u32)us[4] | ((u32)us[5] << 16);
    o[3] = (u32)us[6] | ((u32)us[7] << 16);
}

// ---------------------------------------------------------------------------
// Zero halo positions (h' or t' in {0,31}) of all 1800 planes of y1 and y2.
__global__ __launch_bounds__(128) void zerok(u16* __restrict__ y1, u16* __restrict__ y2)
{
    const int pb = blockIdx.x, tid = threadIdx.x;
    if (tid >= 124) return;
    int hp, tp;
    if (tid < 32)      { hp = 0;        tp = tid; }
    else if (tid < 64) { hp = 31;       tp = tid - 32; }
    else if (tid < 94) { hp = tid - 63; tp = 0; }
    else               { hp = tid - 93; tp = 31; }
    const size_t off = (size_t)pb * PLANE + hp * 1024 + tp * 32;
    const uint4 z = make_uint4(0, 0, 0, 0);
    *(uint4*)((char*)y1 + off)      = z;
    *(uint4*)((char*)y1 + off + 16) = z;
    *(uint4*)((char*)y2 + off)      = z;
    *(uint4*)((char*)y2 + off + 16) = z;
}

// ---------------------------------------------------------------------------
// Layer 0, K-packed: one "tap", 12 MFMAs per wave (unchanged from R13).
__global__ __launch_bounds__(256, 4) void conv0_k(
    const float* __restrict__ x, const uint4* __restrict__ bt,
    const float* __restrict__ bias, void* __restrict__ outp)
{
    __shared__ float E[4][1056];
    const int wgid = blockIdx.x + S * blockIdx.y + 900 * blockIdx.z;
    const int id2  = (wgid & 7) * 450 + (wgid >> 3);
    const int half = id2 & 1;
    int sp = id2 >> 1;
    const int w1i = sp % S; sp /= S;
    const int h1  = sp % S;
    const int b   = sp / S;

    const int tid = threadIdx.x;
    const int lane = tid & 63, wv = tid >> 6;
    const int m = lane & 31, hl = lane >> 5;
    const int rbase = half * 15 + wv * 4;

    uint4 Bs[3];
#pragma unroll
    for (int ss = 0; ss < 3; ++ss) Bs[ss] = bt[ss * 64 + lane];

    int gof[9]; int gokm = 0;
#pragma unroll
    for (int k12 = 0; k12 < 9; ++k12) {
        const int g1 = h1 + k12 / 3 - 1, g2 = w1i + k12 % 3 - 1;
        gof[k12] = 0;
        if (g1 >= 0 && g1 < S && g2 >= 0 && g2 < S) {
            gof[k12] = (g1 * S + g2) * 900; gokm |= 1 << k12;
        }
    }
    const float* xb = x + (size_t)b * S4;

    uint4 F[6];
#pragma unroll
    for (int f = 0; f < 6; ++f) {
        const int hp = rbase + f;
        const bool rk = (hp >= 1 && hp <= 30 && m >= 1 && m <= 30);
        const int ro = (hp - 1) * 30 + (m - 1);
        u16 av[8];
#pragma unroll
        for (int j = 0; j < 8; ++j) av[j] = 0;
        if (hl == 0) {
#pragma unroll
            for (int j = 0; j < 8; ++j) {
                float v = 0.f;
                if (rk && ((gokm >> j) & 1)) v = xb[gof[j] + ro];
                av[j] = f2bf(v);
            }
        } else {
            float v = 0.f;
            if (rk && ((gokm >> 8) & 1)) v = xb[gof[8] + ro];
            av[0] = f2bf(v);
        }
        F[f] = make_uint4((u32)av[0] | ((u32)av[1] << 16),
                          (u32)av[2] | ((u32)av[3] << 16),
                          (u32)av[4] | ((u32)av[5] << 16),
                          (u32)av[6] | ((u32)av[7] << 16));
    }

    f32x16 acc[4];
#pragma unroll
    for (int r = 0; r < 4; ++r)
#pragma unroll
        for (int e = 0; e < 16; ++e) acc[r][e] = 0.f;
#pragma unroll
    for (int ss = 0; ss < 3; ++ss)
#pragma unroll
        for (int r = 0; r < 4; ++r)
            acc[r] = __builtin_amdgcn_mfma_f32_32x32x16_bf16(
                __builtin_bit_cast(bf16x8, F[r + ss]),
                __builtin_bit_cast(bf16x8, Bs[ss]), acc[r], 0, 0, 0);

    float* Ew = E[wv];
    for (int r = 0; r < 4; ++r) {
        if (wv == 3 && r == 3) continue;
#pragma unroll
        for (int gq = 0; gq < 4; ++gq)
#pragma unroll
            for (int r4 = 0; r4 < 4; ++r4)
                Ew[m * 33 + 4 * hl + 8 * gq + r4] = acc[r][gq * 4 + r4];

        const int h2 = rbase + r;
        char* pl = (char*)outp + ((size_t)b * 900 + h1 * S + w1i) * PLANE
                   + (size_t)(h2 + 1) * 1024;
        const int t = lane >> 1, h8 = lane & 1;
        if (t < 30) {
            u32 wo[4];
#pragma unroll
            for (int p = 0; p < 4; ++p) {
                const int c0 = 8 * h8 + 2 * p, c1 = c0 + 1;
                float v0 = 0.f, v1 = 0.f;
                if (c0 < 10)
                    v0 = fmaxf(Ew[c0 * 33 + t] + Ew[(10 + c0) * 33 + t + 1]
                             + Ew[(20 + c0) * 33 + t + 2] + bias[c0], 0.f);
                if (c1 < 10)
                    v1 = fmaxf(Ew[c1 * 33 + t] + Ew[(10 + c1) * 33 + t + 1]
                             + Ew[(20 + c1) * 33 + t + 2] + bias[c1], 0.f);
                wo[p] = (u32)f2bf(v0) | ((u32)f2bf(v1) << 16);
            }
            *(uint4*)(pl + (t + 1) * 32 + h8 * 16) =
                make_uint4(wo[0], wo[1], wo[2], wo[3]);
        }
    }
}

// ---------------------------------------------------------------------------
// Layers 1/2: ping-pong register double-buffered tap loop. Wave wv owns rows
// rbase..rbase+3 (wave 3 row 3 junk). sched_barrier(0) after each load
// cluster pins issue order: loads(state X) -> MFMAs(state Y) with X's 9
// loads in flight (counted vmcnt), no rotate copies to drain them early.
template<int LAYER, bool ACCUM>
__global__ __launch_bounds__(256, 2) void conv_k(
    const void* __restrict__ inp, const u32* __restrict__ ftab,
    const float* __restrict__ bias, void* __restrict__ outp)
{
    __shared__ float E[4][1056];
    const int wgid = blockIdx.x + S * blockIdx.y + 900 * blockIdx.z;
    const int id2  = (wgid & 7) * 450 + (wgid >> 3);
    const int half = id2 & 1;
    int sp = id2 >> 1;
    const int w1i = sp % S; sp /= S;
    const int h1  = sp % S;
    const int b   = sp / S;

    const int tid = threadIdx.x;
    const int lane = tid & 63, wv = tid >> 6;
    const int m = lane & 31, hl = lane >> 5;
    const int rbase = half * 15 + wv * 4;
    const uint4* ft4 = (const uint4*)ftab;

    int rofs[6];
#pragma unroll
    for (int f = 0; f < 6; ++f) {
        int rr = rbase + f; if (rr > 31) rr = 31;
        rofs[f] = rr * 1024;
    }

    int kl[9], nk = 0;
#pragma unroll
    for (int k12 = 0; k12 < 9; ++k12) {
        const int g1 = h1 + k12 / 3 - 1, g2 = w1i + k12 % 3 - 1;
        if (g1 >= 0 && g1 < S && g2 >= 0 && g2 < S)
            kl[nk++] = (g1 * S + g2) | (k12 << 10);
    }

    f32x16 acc[4];
#pragma unroll
    for (int r = 0; r < 4; ++r)
#pragma unroll
        for (int e = 0; e < 16; ++e) acc[r][e] = 0.f;

    auto loadA = [&](uint4* Fd, int g) {
        const char* P = (const char*)inp + ((size_t)b * 900 + g) * PLANE
                        + m * 32 + hl * 16;
#pragma unroll
        for (int f = 0; f < 6; ++f)
            Fd[f] = *(const uint4*)(P + rofs[f]);
    };
    auto loadB = [&](uint4* Bd, int k) {
#pragma unroll
        for (int f = 0; f < 3; ++f) Bd[f] = ft4[(k * 3 + f) * 64 + lane];
    };
    auto mfma12 = [&](const uint4* Fs, const uint4* Bs) {
#pragma unroll
        for (int ss = 0; ss < 3; ++ss)
#pragma unroll
            for (int r = 0; r < 4; ++r)
                acc[r] = __builtin_amdgcn_mfma_f32_32x32x16_bf16(
                    __builtin_bit_cast(bf16x8, Fs[r + ss]),
                    __builtin_bit_cast(bf16x8, Bs[ss]), acc[r], 0, 0, 0);
    };

    uint4 Fa[6], Ba[3], Fb[6], Bb[3];
    loadA(Fa, kl[0] & 1023); loadB(Ba, kl[0] >> 10);

    int ki = 0;
    for (; ki + 2 < nk; ki += 2) {
        loadA(Fb, kl[ki + 1] & 1023); loadB(Bb, kl[ki + 1] >> 10);
        __builtin_amdgcn_sched_barrier(0);
        mfma12(Fa, Ba);                       // vmcnt leaves state-b in flight
        loadA(Fa, kl[ki + 2] & 1023); loadB(Ba, kl[ki + 2] >> 10);
        __builtin_amdgcn_sched_barrier(0);
        mfma12(Fb, Bb);                       // state-a in flight
    }
    if (ki + 1 < nk) {                        // 2 taps left
        loadA(Fb, kl[ki + 1] & 1023); loadB(Bb, kl[ki + 1] >> 10);
        __builtin_amdgcn_sched_barrier(0);
        mfma12(Fa, Ba);
        mfma12(Fb, Bb);
    } else {                                  // 1 tap left
        mfma12(Fa, Ba);
    }

    float* Ew = E[wv];
    for (int r = 0; r < 4; ++r) {
        if (wv == 3 && r == 3) continue;
#pragma unroll
        for (int gq = 0; gq < 4; ++gq)
#pragma unroll
            for (int r4 = 0; r4 < 4; ++r4)
                Ew[m * 33 + 4 * hl + 8 * gq + r4] = acc[r][gq * 4 + r4];

        const int h2 = rbase + r;
        if (LAYER <= 1) {
            char* pl = (char*)outp + ((size_t)b * 900 + h1 * S + w1i) * PLANE
                       + (size_t)(h2 + 1) * 1024;
            const int t = lane >> 1, h8 = lane & 1;
            if (t < 30) {
                u32 wo[4];
#pragma unroll
                for (int p = 0; p < 4; ++p) {
                    const int c0 = 8 * h8 + 2 * p, c1 = c0 + 1;
                    float v0 = 0.f, v1 = 0.f;
                    if (c0 < 10)
                        v0 = fmaxf(Ew[c0 * 33 + t] + Ew[(10 + c0) * 33 + t + 1]
                                 + Ew[(20 + c0) * 33 + t + 2] + bias[c0], 0.f);
                    if (c1 < 10)
                        v1 = fmaxf(Ew[c1 * 33 + t] + Ew[(10 + c1) * 33 + t + 1]
                                 + Ew[(20 + c1) * 33 + t + 2] + bias[c1], 0.f);
                    wo[p] = (u32)f2bf(v0) | ((u32)f2bf(v1) << 16);
                }
                *(uint4*)(pl + (t + 1) * 32 + h8 * 16) =
                    make_uint4(wo[0], wo[1], wo[2], wo[3]);
            }
        } else {
            if (lane < 30) {
                const int t = lane;
                float v = Ew[t] + Ew[330 + t + 1] + Ew[660 + t + 2] + bias[0];
                v = fmaxf(v, 0.f);
                float* o = (float*)outp + (size_t)b * S4
                           + (size_t)(h1 * S + w1i) * 900 + h2 * 30 + t;
                if (ACCUM) *o += v; else *o = v;
            }
        }
    }
}

// ---------------------------------------------------------------------------
extern "C" void kernel_launch(void* const* d_in, const int* in_sizes, int n_in,
                              void* d_out, int out_size, void* d_ws, size_t ws_size,
                              hipStream_t stream)
{
    const float* x   = (const float*)d_in[0];
    const float* w1p = (const float*)d_in[1];
    const float* b1p = (const float*)d_in[2];
    const float* w2p = (const float*)d_in[3];
    const float* b2p = (const float*)d_in[4];
    const float* w3p = (const float*)d_in[5];
    const float* b3p = (const float*)d_in[6];
    float* out = (float*)d_out;

    // ws: fragtab (6*27*64 + 2*3*64) uint4 = 172032 B | y1 59 MB | y2 59 MB
    u32* ft = (u32*)d_ws;
    const uint4* ftL0 = (const uint4*)d_ws + 6 * 27 * 64;
    u16* y1 = (u16*)((char*)d_ws + 172032);
    u16* y2 = (u16*)((char*)y1 + YBYTES);

    fragprep_k<<<42, 256, 0, stream>>>(ft, w1p, w2p, w3p);
    zerok<<<1800, 128, 0, stream>>>(y1, y2);

    dim3 grid(S, S, 4), blk(256);
    for (int br = 0; br < 2; ++br) {
        const u32* f2 = ft + (size_t)(2 + br) * 27 * 64 * 4;
        const u32* f3 = ft + (size_t)(4 + br) * 27 * 64 * 4;
        conv0_k<<<grid, blk, 0, stream>>>(x, ftL0 + br * 192, b1p, (void*)y1);
        conv_k<1, false><<<grid, blk, 0, stream>>>(y1, f2, b2p, (void*)y2);
        if (br == 0)
            conv_k<2, false><<<grid, blk, 0, stream>>>(y2, f3, b3p, (void*)out);
        else
            conv_k<2, true><<<grid, blk, 0, stream>>>(y2, f3, b3p, (void*)out);
    }
}